// Round 17
// baseline (1305.320 us; speedup 1.0000x reference)
//
#include <hip/hip_runtime.h>
#include <math.h>

#define HH 96
#define WW 96
#define HW 9216
#define TT 5

typedef __attribute__((ext_vector_type(8))) short bf16x8;
typedef __attribute__((ext_vector_type(4))) float f32x4;

__device__ __forceinline__ float sigf(float x) { return 1.0f / (1.0f + expf(-x)); }
__device__ __forceinline__ unsigned short bhi(float x) {
    return (unsigned short)(__float_as_uint(x) >> 16);
}
__device__ __forceinline__ unsigned short blo(float x) {
    float h = __uint_as_float(__float_as_uint(x) & 0xffff0000u);
    return (unsigned short)(__float_as_uint(x - h) >> 16);
}
__device__ __forceinline__ float b2f(unsigned short u) {
    return __uint_as_float(((unsigned)u) << 16);
}

// ---------------------------------------------------------------------------
// Weight expansion: src [OC][IC][9] fp32 -> dst [9][OCP][2][IC] bf16 hi/lo.
// ---------------------------------------------------------------------------
__global__ __launch_bounds__(256) void wexp3_kernel(
    const float* __restrict__ w, unsigned short* __restrict__ dst,
    int OC, int OCP, int IC)
{
    long i = (long)blockIdx.x * 256 + threadIdx.x;
    int ic = (int)(i % IC);
    long r = i / IC;
    int oc = (int)(r % OCP);
    int tap = (int)(r / OCP);
    float v = (oc < OC) ? w[((long)oc * IC + ic) * 9 + tap] : 0.f;
    long base = (((long)tap * OCP + oc) * 2) * IC + ic;
    dst[base] = bhi(v);
    dst[base + IC] = blo(v);
}

// dcn_w [128][576] (576 = c*9+k) -> [128][2][576] with K re-ordered k-major:
// dst K-slot (k*64 + c) = src (c*9 + k).
__global__ __launch_bounds__(256) void wexp1_kernel(
    const float* __restrict__ w, unsigned short* __restrict__ dst)
{
    int i = blockIdx.x * 256 + threadIdx.x;   // over 128*576 dst slots
    int slot = i % 576;                        // k*64 + c
    int oc = i / 576;
    int k = slot >> 6, c = slot & 63;
    float v = w[(long)oc * 576 + c * 9 + k];
    dst[((long)oc * 2) * 576 + slot] = bhi(v);
    dst[((long)oc * 2 + 1) * 576 + slot] = blo(v);
}

// input [b][t][64][HW] fp32 -> xbf [(t*2+b)][p][64] bf16
__global__ __launch_bounds__(256) void xprep_kernel(
    const float* __restrict__ input, unsigned short* __restrict__ xbf)
{
    long i = (long)blockIdx.x * 256 + threadIdx.x;
    int p = (int)(i % HW);
    long r = i / HW;
    int c = (int)(r % 64);
    long bt = r / 64;
    int b = (int)(bt / TT), t = (int)(bt % TT);
    float v = input[i];
    xbf[(((long)(t * 2 + b) * HW) + p) * 64 + c] = bhi(v);
}

// ===========================================================================
// R17: conv1x1 TILE HALVING for TLP. 1x1 conv has NO halo and w1 is L2-
// resident, so the R2 "smaller tile = more re-fetch" trap doesn't apply.
// 64px/512thr/576blk (2.25/CU, occ 27%) -> 32px/256thr/1152blk (4.5/CU):
// doubles independent gather streams per CU. MFMA: 4 waves, wave owns oc
// blocks {2w, 2w+1}, acc[2][2]. Per-acc order (cb, sub, hi/lo) unchanged ->
// bitwise-identical. XCD swizzle bijective (1152 = 8 x 144).
// big/om/fuse/cat at R16 measured-best configs.
// ===========================================================================

// ---------------------------------------------------------------------------
// Fuse conv: x (single, ic 0..63) + h (hl, ic 64..127) -> comb bf16 NHWC.
// 6x16 tile, 4 waves, wave owns one oc-16 block. acc[6]=24 VGPR, rolling-B.
// ---------------------------------------------------------------------------
__global__ __launch_bounds__(256) void fuse_conv(
    const unsigned short* __restrict__ xbf,
    const unsigned short* __restrict__ hbuf,
    const unsigned short* __restrict__ Wf,   // [9][64][2][128]
    const float* __restrict__ bias,
    unsigned short* __restrict__ comb,
    int t0, int t1)
{
    __shared__ unsigned short sX[144 * 200];
    const int tid = threadIdx.x;
    const int wave = tid >> 6, lane = tid & 63;
    const int m = lane & 15, quad = lane >> 4;
    const int tY = blockIdx.x / 6, tX = blockIdx.x % 6;   // tY 0..15
    const int z = blockIdx.z;
    const int imgX = ((z < 2) ? t0 : t1) * 2 + (z & 1);

    const unsigned short* xb = xbf + (long)imgX * HW * 64;
    const unsigned short* hb = hbuf + (long)z * HW * 128;

    for (int i = tid; i < 144 * 24; i += 256) {
        int cell = i / 24, v = i - cell * 24;
        int row = cell / 18, col = cell - row * 18;
        int gy = tY * 6 + row - 1, gx = tX * 16 + col - 1;
        bool ok = (gy >= 0 && gy < HH && gx >= 0 && gx < WW);
        int p = gy * WW + gx;
        bf16x8 val = (bf16x8){0,0,0,0,0,0,0,0};
        int dst;
        if (v < 8) {
            if (ok) val = *(const bf16x8*)(xb + (long)p * 64 + v * 8);
            dst = cell * 200 + v * 8;
        } else {
            int v2 = v - 8;
            int pl = v2 >> 3, c = (v2 & 7) >> 2, g = v2 & 3;
            // hbuf record: [16 groups][hi8|lo8]; channels c*32+g*8 = group c*4+g
            if (ok) val = *(const bf16x8*)(hb + (long)p * 128 + (c * 4 + g) * 16 + pl * 8);
            dst = cell * 200 + 64 + (c * 2 + pl) * 32 + g * 8;
        }
        *(bf16x8*)&sX[dst] = val;
    }
    __syncthreads();

    f32x4 acc[6];
#pragma unroll
    for (int nf = 0; nf < 6; ++nf) acc[nf] = (f32x4){0.f, 0.f, 0.f, 0.f};

    // part 1: x channels (single precision), c = 0,1
#pragma unroll
    for (int c = 0; c < 2; ++c) {
#pragma unroll
        for (int kx = 0; kx < 3; ++kx) {
            bf16x8 Ah[3], Al[3];
#pragma unroll
            for (int ky = 0; ky < 3; ++ky) {
                const unsigned short* wp = Wf + (((long)(ky * 3 + kx) * 64 + wave * 16 + m) * 2) * 128 + c * 32 + quad * 8;
                Ah[ky] = *(const bf16x8*)wp;
                Al[ky] = *(const bf16x8*)(wp + 128);
            }
            bf16x8 B[8];
#pragma unroll
            for (int r = 0; r < 3; ++r)
                B[r] = *(const bf16x8*)&sX[(r * 18 + kx + m) * 200 + c * 32 + quad * 8];
#pragma unroll
            for (int nf = 0; nf < 6; ++nf) {
                if (nf) {
                    int r = nf + 2;
                    B[r] = *(const bf16x8*)&sX[(r * 18 + kx + m) * 200 + c * 32 + quad * 8];
                }
#pragma unroll
                for (int ky = 0; ky < 3; ++ky) {
                    acc[nf] = __builtin_amdgcn_mfma_f32_16x16x32_bf16(Ah[ky], B[nf + ky], acc[nf], 0, 0, 0);
                    acc[nf] = __builtin_amdgcn_mfma_f32_16x16x32_bf16(Al[ky], B[nf + ky], acc[nf], 0, 0, 0);
                }
            }
        }
    }
    // part 2: h channels (hl), c = 0,1
#pragma unroll
    for (int c = 0; c < 2; ++c) {
#pragma unroll
        for (int kx = 0; kx < 3; ++kx) {
            bf16x8 Ah[3], Al[3];
#pragma unroll
            for (int ky = 0; ky < 3; ++ky) {
                const unsigned short* wp = Wf + (((long)(ky * 3 + kx) * 64 + wave * 16 + m) * 2) * 128 + (2 + c) * 32 + quad * 8;
                Ah[ky] = *(const bf16x8*)wp;
                Al[ky] = *(const bf16x8*)(wp + 128);
            }
            bf16x8 Bh[8], Bl[8];
#pragma unroll
            for (int r = 0; r < 3; ++r) {
                int base = (r * 18 + kx + m) * 200 + 64 + (c * 2) * 32 + quad * 8;
                Bh[r] = *(const bf16x8*)&sX[base];
                Bl[r] = *(const bf16x8*)&sX[base + 32];
            }
#pragma unroll
            for (int nf = 0; nf < 6; ++nf) {
                if (nf) {
                    int r = nf + 2;
                    int base = (r * 18 + kx + m) * 200 + 64 + (c * 2) * 32 + quad * 8;
                    Bh[r] = *(const bf16x8*)&sX[base];
                    Bl[r] = *(const bf16x8*)&sX[base + 32];
                }
#pragma unroll
                for (int ky = 0; ky < 3; ++ky) {
                    acc[nf] = __builtin_amdgcn_mfma_f32_16x16x32_bf16(Ah[ky], Bh[nf + ky], acc[nf], 0, 0, 0);
                    acc[nf] = __builtin_amdgcn_mfma_f32_16x16x32_bf16(Al[ky], Bh[nf + ky], acc[nf], 0, 0, 0);
                    acc[nf] = __builtin_amdgcn_mfma_f32_16x16x32_bf16(Ah[ky], Bl[nf + ky], acc[nf], 0, 0, 0);
                }
            }
        }
    }

    int ocl = wave * 16 + quad * 4;
    float b0 = bias[ocl], b1 = bias[ocl + 1], b2 = bias[ocl + 2], b3 = bias[ocl + 3];
#pragma unroll
    for (int nf = 0; nf < 6; ++nf) {
        int p = (tY * 6 + nf) * WW + tX * 16 + m;
        ushort4 hv;
        hv.x = bhi(acc[nf].x + b0); hv.y = bhi(acc[nf].y + b1);
        hv.z = bhi(acc[nf].z + b2); hv.w = bhi(acc[nf].w + b3);
        *(ushort4*)&comb[((long)z * HW + p) * 64 + ocl] = hv;
    }
}

// ---------------------------------------------------------------------------
// om conv: comb (single, IC=64) -> om fp32 NCHW (216 of 256 oc).
// R8-recipe clone (R12-measured win): 6x16 tile, 16-wave block, wave owns
// one oc-16 block, acc[6], rolling-3 B window, 8:1 MFMA:load.
// ---------------------------------------------------------------------------
__global__ __launch_bounds__(1024) void om_conv(
    const unsigned short* __restrict__ comb,
    const unsigned short* __restrict__ Wo,   // [9][256][2][64]
    const float* __restrict__ bias,
    float* __restrict__ om)                  // [z][216][HW]
{
    __shared__ unsigned short sX[144 * 72];
    const int tid = threadIdx.x;
    const int wave = tid >> 6, lane = tid & 63;
    const int m = lane & 15, quad = lane >> 4;
    const int tY = blockIdx.x / 6, tX = blockIdx.x % 6;   // tY 0..15
    const int z = blockIdx.z;
    const unsigned short* cbp = comb + (long)z * HW * 64;

    for (int i = tid; i < 144 * 8; i += 1024) {
        int cell = i >> 3, v = i & 7;
        int row = cell / 18, col = cell - row * 18;
        int gy = tY * 6 + row - 1, gx = tX * 16 + col - 1;
        bf16x8 val = (bf16x8){0,0,0,0,0,0,0,0};
        if (gy >= 0 && gy < HH && gx >= 0 && gx < WW)
            val = *(const bf16x8*)(cbp + (long)(gy * WW + gx) * 64 + v * 8);
        *(bf16x8*)&sX[cell * 72 + v * 8] = val;
    }
    __syncthreads();

    if (wave * 16 >= 216) return;   // oc blocks 14,15 are pure padding

    f32x4 acc[6];
#pragma unroll
    for (int nf = 0; nf < 6; ++nf) acc[nf] = (f32x4){0.f, 0.f, 0.f, 0.f};

#pragma unroll
    for (int c = 0; c < 2; ++c) {
#pragma unroll
        for (int kx = 0; kx < 3; ++kx) {
            bf16x8 Ah[3], Al[3];
#pragma unroll
            for (int ky = 0; ky < 3; ++ky) {
                const unsigned short* wp = Wo + (((long)(ky * 3 + kx) * 256 + wave * 16 + m) * 2) * 64 + c * 32 + quad * 8;
                Ah[ky] = *(const bf16x8*)wp;
                Al[ky] = *(const bf16x8*)(wp + 64);
            }
            bf16x8 B[8];
#pragma unroll
            for (int r = 0; r < 3; ++r)
                B[r] = *(const bf16x8*)&sX[(r * 18 + kx + m) * 72 + c * 32 + quad * 8];
#pragma unroll
            for (int nf = 0; nf < 6; ++nf) {
                if (nf) {
                    int r = nf + 2;
                    B[r] = *(const bf16x8*)&sX[(r * 18 + kx + m) * 72 + c * 32 + quad * 8];
                }
#pragma unroll
                for (int ky = 0; ky < 3; ++ky) {
                    acc[nf] = __builtin_amdgcn_mfma_f32_16x16x32_bf16(Ah[ky], B[nf + ky], acc[nf], 0, 0, 0);
                    acc[nf] = __builtin_amdgcn_mfma_f32_16x16x32_bf16(Al[ky], B[nf + ky], acc[nf], 0, 0, 0);
                }
            }
        }
    }

#pragma unroll
    for (int reg = 0; reg < 4; ++reg) {
        int oc = wave * 16 + quad * 4 + reg;
        if (oc < 216) {
            float bv = bias[oc];
#pragma unroll
            for (int nf = 0; nf < 6; ++nf) {
                int p = (tY * 6 + nf) * WW + tX * 16 + m;
                om[((long)z * 216 + oc) * HW + p] = acc[nf][reg] + bv;
            }
        }
    }
}

// ---------------------------------------------------------------------------
// FUSED deformable-sampling + 1x1 DCN einsum. 32-px tiles, 256 threads,
// 1152 blocks (4.5/CU) for 2x gather-latency TLP (1x1: no halo, w1 is
// L2-resident -> no re-fetch penalty). 4 waves; wave owns oc-16 blocks
// {2w, 2w+1}: acc[2][2]. Per-acc order (cb, sub, hi/lo) unchanged ->
// bitwise-identical. hbuf record [16 groups][hi8|lo8] (R15 win).
// ---------------------------------------------------------------------------
__global__ __launch_bounds__(256) void conv1x1_fused(
    const unsigned short* __restrict__ hbuf,  // [4][p][16][2][8] group-interleaved
    const float* __restrict__ om,             // [4][216][HW]
    const unsigned short* __restrict__ w1,    // [128][2][576] k-major
    const float* __restrict__ bias,
    unsigned short* __restrict__ fused)       // [z][p][256] hl
{
    __shared__ unsigned short sX[32 * 76];
    const int tid  = threadIdx.x;
    const int wave = tid >> 6, lane = tid & 63;
    const int m = lane & 15, quad = lane >> 4;

    // bijective XCD swizzle over 1152 = 8 XCDs x 144 chunks
    const int bid = blockIdx.x;
    const int work = (bid & 7) * 144 + (bid >> 3);
    const int zz = work / 288;
    const int pt = work - zz * 288;          // 32-px tile index

    const float* omb = om + (long)zz * 216 * HW;
    const unsigned short* hz = hbuf + (long)zz * HW * 128;

    const int g0 = tid >> 5;        // 0..7  (channel group)
    const int cellb = tid & 31;     // 0..31 (pixel within tile)

    // Bilinear-sample 8 channels (group g0) at pixel p=pt*32+cell, tap cb.
    // Expression-identical to the original sampler -> bitwise-same bf16.
    auto sample = [&](int cell, int cb) -> bf16x8 {
        int p = pt * 32 + cell;
        int y = p / WW, x = p - y * WW;
        int ky = cb / 3, kx = cb - ky * 3;
        float offy = omb[(g0 * 18 + cb * 2) * HW + p];
        float offx = omb[(g0 * 18 + cb * 2 + 1) * HW + p];
        float mm = sigf(omb[(144 + g0 * 9 + cb) * HW + p]);
        float py = (float)(y + ky - 1) + offy;
        float px = (float)(x + kx - 1) + offx;
        float y0f = floorf(py), x0f = floorf(px);
        float wy = py - y0f, wx = px - x0f;
        int y0 = (int)y0f, x0 = (int)x0f;
        int y1 = y0 + 1, x1 = x0 + 1;
        bool vy0 = (y0 >= 0) && (y0 < HH), vy1 = (y1 >= 0) && (y1 < HH);
        bool vx0 = (x0 >= 0) && (x0 < WW), vx1 = (x1 >= 0) && (x1 < WW);
        int cy0 = min(max(y0, 0), HH - 1), cy1 = min(max(y1, 0), HH - 1);
        int cx0 = min(max(x0, 0), WW - 1), cx1 = min(max(x1, 0), WW - 1);
        long i00 = cy0 * WW + cx0, i01 = cy0 * WW + cx1;
        long i10 = cy1 * WW + cx0, i11 = cy1 * WW + cx1;
        float w00 = (1.f - wy) * (1.f - wx) * ((vy0 && vx0) ? mm : 0.f);
        float w01 = (1.f - wy) * wx         * ((vy0 && vx1) ? mm : 0.f);
        float w10 = wy * (1.f - wx)         * ((vy1 && vx0) ? mm : 0.f);
        float w11 = wy * wx                 * ((vy1 && vx1) ? mm : 0.f);
        // group-interleaved record: hi at p*128 + g0*16, lo at +8 (same 64B line)
        const unsigned short* hzb = hz + g0 * 16;
        bf16x8 h00 = *(const bf16x8*)(hzb + i00 * 128);
        bf16x8 l00 = *(const bf16x8*)(hzb + i00 * 128 + 8);
        bf16x8 h01 = *(const bf16x8*)(hzb + i01 * 128);
        bf16x8 l01 = *(const bf16x8*)(hzb + i01 * 128 + 8);
        bf16x8 h10 = *(const bf16x8*)(hzb + i10 * 128);
        bf16x8 l10 = *(const bf16x8*)(hzb + i10 * 128 + 8);
        bf16x8 h11 = *(const bf16x8*)(hzb + i11 * 128);
        bf16x8 l11 = *(const bf16x8*)(hzb + i11 * 128 + 8);
        bf16x8 outv;
#pragma unroll
        for (int cg = 0; cg < 8; ++cg) {
            float v00 = b2f((unsigned short)h00[cg]) + b2f((unsigned short)l00[cg]);
            float v01 = b2f((unsigned short)h01[cg]) + b2f((unsigned short)l01[cg]);
            float v10 = b2f((unsigned short)h10[cg]) + b2f((unsigned short)l10[cg]);
            float v11 = b2f((unsigned short)h11[cg]) + b2f((unsigned short)l11[cg]);
            float v = w00 * v00 + w01 * v01 + w10 * v10 + w11 * v11;
            outv[cg] = (short)bhi(v);
        }
        return outv;
    };

    f32x4 acc[2][2];
#pragma unroll
    for (int mm = 0; mm < 2; ++mm)
#pragma unroll
        for (int nf = 0; nf < 2; ++nf) acc[mm][nf] = (f32x4){0.f, 0.f, 0.f, 0.f};

    for (int cb = 0; cb < 9; ++cb) {
        if (cb) __syncthreads();
        bf16x8 R0 = sample(cellb, cb);
        *(bf16x8*)&sX[cellb * 76 + g0 * 8] = R0;
        __syncthreads();

        bf16x8 Bv[2][2];
#pragma unroll
        for (int sub = 0; sub < 2; ++sub)
#pragma unroll
            for (int nf = 0; nf < 2; ++nf)
                Bv[sub][nf] = *(const bf16x8*)&sX[(nf * 16 + m) * 76 + sub * 32 + quad * 8];
        bf16x8 Ah[2][2], Al[2][2];
#pragma unroll
        for (int sub = 0; sub < 2; ++sub)
#pragma unroll
            for (int mm = 0; mm < 2; ++mm) {
                const unsigned short* wp = w1 + ((long)((wave * 2 + mm) * 16 + m) * 2) * 576
                                           + cb * 64 + sub * 32 + quad * 8;
                Ah[sub][mm] = *(const bf16x8*)wp;
                Al[sub][mm] = *(const bf16x8*)(wp + 576);
            }
#pragma unroll
        for (int sub = 0; sub < 2; ++sub)
#pragma unroll
            for (int mm = 0; mm < 2; ++mm)
#pragma unroll
                for (int nf = 0; nf < 2; ++nf) {
                    acc[mm][nf] = __builtin_amdgcn_mfma_f32_16x16x32_bf16(
                        Ah[sub][mm], Bv[sub][nf], acc[mm][nf], 0, 0, 0);
                    acc[mm][nf] = __builtin_amdgcn_mfma_f32_16x16x32_bf16(
                        Al[sub][mm], Bv[sub][nf], acc[mm][nf], 0, 0, 0);
                }
    }

#pragma unroll
    for (int mm = 0; mm < 2; ++mm) {
        int ocl = (wave * 2 + mm) * 16 + quad * 4;
        float b0 = bias[ocl], b1 = bias[ocl + 1], b2 = bias[ocl + 2], b3 = bias[ocl + 3];
#pragma unroll
        for (int nf = 0; nf < 2; ++nf) {
            int p = pt * 32 + nf * 16 + m;
            float v0 = fmaxf(acc[mm][nf].x + b0, 0.f);
            float v1 = fmaxf(acc[mm][nf].y + b1, 0.f);
            float v2 = fmaxf(acc[mm][nf].z + b2, 0.f);
            float v3 = fmaxf(acc[mm][nf].w + b3, 0.f);
            unsigned short* op = fused + ((long)zz * HW + p) * 256 + ocl;
            ushort4 hv, lv;
            hv.x = bhi(v0); hv.y = bhi(v1); hv.z = bhi(v2); hv.w = bhi(v3);
            lv.x = blo(v0); lv.y = blo(v1); lv.z = blo(v2); lv.w = blo(v3);
            *(ushort4*)op = hv;
            *(ushort4*)(op + 128) = lv;
        }
    }
}

// ---------------------------------------------------------------------------
// Big conv (IC=128 hl, OC=256) FUSED with LSTM gates. Z-PAIRED:
// block = one 6x16 tile x two z-planes (zp, zp+2), both staged in LDS
// (2 x 38016 ush = 152064 B, 1 block/CU). Per (c,kx): 6 weight loads feed
// 2x54 = 108 MFMAs. Grid 96x2 = 192 blocks. R16-measured win; unchanged.
// ---------------------------------------------------------------------------
__global__ __launch_bounds__(1024) void big_conv_gates(
    const unsigned short* __restrict__ fusedb,  // [z][p][256] hl
    const unsigned short* __restrict__ Wc,      // [9][256][2][128]
    const float* __restrict__ bias,
    float* __restrict__ cst,                    // [z][p][64] fp32
    unsigned short* __restrict__ hbuf,          // [z][p][16][2][8] group-interleaved
    unsigned short* __restrict__ hseq,          // [(t*2+b)][p][128]
    int t0, int t1)
{
    // 2 planes x 144 cells x 264 ush = 152064 B. Gates region (after both
    // K-loops) reuses the front: 3 x 96 x 68 floats = 78336 B <= 152064.
    __shared__ unsigned short sX[2][144 * 264];
    const int tid = threadIdx.x;
    const int wave = tid >> 6, lane = tid & 63;
    const int m = lane & 15, quad = lane >> 4;
    const int tY = blockIdx.x / 6, tX = blockIdx.x % 6;   // tY 0..15
    const int zp = blockIdx.z;                             // 0,1: z = zp + zi*2

#pragma unroll
    for (int zi = 0; zi < 2; ++zi) {
        const unsigned short* fb = fusedb + (long)(zp + zi * 2) * HW * 256;
        for (int i = tid; i < 144 * 32; i += 1024) {
            int cell = i >> 5, v = i & 31;
            int row = cell / 18, col = cell - row * 18;
            int gy = tY * 6 + row - 1, gx = tX * 16 + col - 1;
            int pl = v >> 4, c = (v & 15) >> 2, g = v & 3;
            bf16x8 val = (bf16x8){0,0,0,0,0,0,0,0};
            if (gy >= 0 && gy < HH && gx >= 0 && gx < WW)
                val = *(const bf16x8*)(fb + (long)(gy * WW + gx) * 256 + pl * 128 + c * 32 + g * 8);
            *(bf16x8*)&sX[zi][cell * 264 + (c * 2 + pl) * 32 + g * 8] = val;
        }
    }
    __syncthreads();

    f32x4 acc[2][6];
#pragma unroll
    for (int zi = 0; zi < 2; ++zi)
#pragma unroll
        for (int nf = 0; nf < 6; ++nf) acc[zi][nf] = (f32x4){0.f, 0.f, 0.f, 0.f};

#pragma unroll
    for (int c = 0; c < 4; ++c) {
#pragma unroll
        for (int kx = 0; kx < 3; ++kx) {
            bf16x8 Ah[3], Al[3];
#pragma unroll
            for (int ky = 0; ky < 3; ++ky) {
                const unsigned short* wp = Wc + (((long)(ky * 3 + kx) * 256 + wave * 16 + m) * 2) * 128 + c * 32 + quad * 8;
                Ah[ky] = *(const bf16x8*)wp;
                Al[ky] = *(const bf16x8*)(wp + 128);
            }
#pragma unroll
            for (int zi = 0; zi < 2; ++zi) {
                bf16x8 Bh[8], Bl[8];
#pragma unroll
                for (int r = 0; r < 3; ++r) {
                    int base = (r * 18 + kx + m) * 264 + (c * 2) * 32 + quad * 8;
                    Bh[r] = *(const bf16x8*)&sX[zi][base];
                    Bl[r] = *(const bf16x8*)&sX[zi][base + 32];
                }
#pragma unroll
                for (int nf = 0; nf < 6; ++nf) {
                    if (nf) {
                        int r = nf + 2;
                        int base = (r * 18 + kx + m) * 264 + (c * 2) * 32 + quad * 8;
                        Bh[r] = *(const bf16x8*)&sX[zi][base];
                        Bl[r] = *(const bf16x8*)&sX[zi][base + 32];
                    }
#pragma unroll
                    for (int ky = 0; ky < 3; ++ky) {
                        acc[zi][nf] = __builtin_amdgcn_mfma_f32_16x16x32_bf16(Ah[ky], Bh[nf + ky], acc[zi][nf], 0, 0, 0);
                        acc[zi][nf] = __builtin_amdgcn_mfma_f32_16x16x32_bf16(Al[ky], Bh[nf + ky], acc[zi][nf], 0, 0, 0);
                        acc[zi][nf] = __builtin_amdgcn_mfma_f32_16x16x32_bf16(Ah[ky], Bl[nf + ky], acc[zi][nf], 0, 0, 0);
                    }
                }
            }
        }
    }

    // ---- gates epilogue (per z-plane; gates region reuses staging LDS) ----
    // wave w owns oc block w: ci = w0-3, cf = w4-7, co = w8-11, cg = w12-15.
    float* sG = (float*)&sX[0][0];
    float ba[4];
    {
        int oc0 = wave * 16 + quad * 4;
#pragma unroll
        for (int r = 0; r < 4; ++r) ba[r] = bias[oc0 + r];
    }
#pragma unroll
    for (int zi = 0; zi < 2; ++zi) {
        const int z = zp + zi * 2;
        __syncthreads();   // staging reads (zi=0) / prior gate reads (zi=1) done
        if (wave >= 4) {
            int reg = (wave >> 2) - 1;            // 0=cf, 1=co, 2=cg
            int chb = (wave & 3) * 16 + quad * 4;
#pragma unroll
            for (int nf = 0; nf < 6; ++nf) {
                int px = nf * 16 + m;
                float* f = &sG[reg * 96 * 68 + (long)px * 68 + chb];
#pragma unroll
                for (int r = 0; r < 4; ++r) f[r] = acc[zi][nf][r] + ba[r];
            }
        }
        __syncthreads();
        if (wave < 4) {
            int t = (zi == 0) ? t0 : t1;
            int b = zp & 1, dir = zi;
            int chb = wave * 16 + quad * 4;
            unsigned short* hsq = hseq + ((long)(t * 2 + b) * HW) * 128 + dir * 64;
#pragma unroll
            for (int nf = 0; nf < 6; ++nf) {
                int px = nf * 16 + m;
                int p = (tY * 6 + nf) * WW + tX * 16 + m;
                float4 cf4 = *(float4*)&sG[0 * 96 * 68 + (long)px * 68 + chb];
                float4 co4 = *(float4*)&sG[1 * 96 * 68 + (long)px * 68 + chb];
                float4 cg4 = *(float4*)&sG[2 * 96 * 68 + (long)px * 68 + chb];
                float* cp = &cst[((long)z * HW + p) * 64 + chb];
                float4 cold = *(float4*)cp;
                float cfv[4] = {cf4.x, cf4.y, cf4.z, cf4.w};
                float cov[4] = {co4.x, co4.y, co4.z, co4.w};
                float cgv[4] = {cg4.x, cg4.y, cg4.z, cg4.w};
                float coldv[4] = {cold.x, cold.y, cold.z, cold.w};
                float c2v[4], h2v[4];
#pragma unroll
                for (int r = 0; r < 4; ++r) {
                    float civ = acc[zi][nf][r] + ba[r];
                    float c2 = sigf(cfv[r]) * coldv[r] + sigf(civ) * tanhf(cgv[r]);
                    float h2 = sigf(cov[r]) * tanhf(c2);
                    c2v[r] = c2; h2v[r] = h2;
                }
                *(float4*)cp = (float4){c2v[0], c2v[1], c2v[2], c2v[3]};
                // group-interleaved hbuf record: hi at group*16 + (chb&7), lo at +8
                unsigned short* hp = hbuf + ((long)z * HW + p) * 128 + (chb >> 3) * 16 + (chb & 7);
                ushort4 hv = {bhi(h2v[0]), bhi(h2v[1]), bhi(h2v[2]), bhi(h2v[3])};
                ushort4 lv = {blo(h2v[0]), blo(h2v[1]), blo(h2v[2]), blo(h2v[3])};
                *(ushort4*)hp = hv;
                *(ushort4*)(hp + 8) = lv;
                *(ushort4*)&hsq[(long)p * 128 + chb] = hv;
            }
        }
    }
}

// ---------------------------------------------------------------------------
// cat conv: hseq (single-plane, IC=128) -> out fp32 NCHW with (t,b) permute.
// 6x16 tile: grid 96x10 = 960 blocks, acc[6], rolling-B.
// ---------------------------------------------------------------------------
__global__ __launch_bounds__(256) void cat_conv(
    const unsigned short* __restrict__ hseq,
    const unsigned short* __restrict__ Wk,     // [9][64][2][128]
    const float* __restrict__ bias,
    float* __restrict__ out)
{
    __shared__ unsigned short sX[144 * 136];
    const int tid = threadIdx.x;
    const int wave = tid >> 6, lane = tid & 63;
    const int m = lane & 15, quad = lane >> 4;
    const int tY = blockIdx.x / 6, tX = blockIdx.x % 6;   // tY 0..15
    const int img = blockIdx.z;
    const unsigned short* hp = hseq + (long)img * HW * 128;

    for (int i = tid; i < 144 * 16; i += 256) {
        int cell = i >> 4, v = i & 15;
        int row = cell / 18, col = cell - row * 18;
        int gy = tY * 6 + row - 1, gx = tX * 16 + col - 1;
        bf16x8 val = (bf16x8){0,0,0,0,0,0,0,0};
        if (gy >= 0 && gy < HH && gx >= 0 && gx < WW)
            val = *(const bf16x8*)(hp + (long)(gy * WW + gx) * 128 + v * 8);
        *(bf16x8*)&sX[cell * 136 + v * 8] = val;
    }
    __syncthreads();

    f32x4 acc[6];
#pragma unroll
    for (int nf = 0; nf < 6; ++nf) acc[nf] = (f32x4){0.f, 0.f, 0.f, 0.f};

#pragma unroll
    for (int c = 0; c < 4; ++c) {
#pragma unroll
        for (int kx = 0; kx < 3; ++kx) {
            bf16x8 Ah[3], Al[3];
#pragma unroll
            for (int ky = 0; ky < 3; ++ky) {
                const unsigned short* wp = Wk + (((long)(ky * 3 + kx) * 64 + wave * 16 + m) * 2) * 128 + c * 32 + quad * 8;
                Ah[ky] = *(const bf16x8*)wp;
                Al[ky] = *(const bf16x8*)(wp + 128);
            }
            bf16x8 B[8];
#pragma unroll
            for (int r = 0; r < 3; ++r)
                B[r] = *(const bf16x8*)&sX[(r * 18 + kx + m) * 136 + c * 32 + quad * 8];
#pragma unroll
            for (int nf = 0; nf < 6; ++nf) {
                if (nf) {
                    int r = nf + 2;
                    B[r] = *(const bf16x8*)&sX[(r * 18 + kx + m) * 136 + c * 32 + quad * 8];
                }
#pragma unroll
                for (int ky = 0; ky < 3; ++ky) {
                    acc[nf] = __builtin_amdgcn_mfma_f32_16x16x32_bf16(Ah[ky], B[nf + ky], acc[nf], 0, 0, 0);
                    acc[nf] = __builtin_amdgcn_mfma_f32_16x16x32_bf16(Al[ky], B[nf + ky], acc[nf], 0, 0, 0);
                }
            }
        }
    }

    int t = img >> 1, b = img & 1;
    long imgOut = (long)(b * TT + t) * 64 * HW;
#pragma unroll
    for (int reg = 0; reg < 4; ++reg) {
        int oc = wave * 16 + quad * 4 + reg;
        float bv = bias[oc];
#pragma unroll
        for (int nf = 0; nf < 6; ++nf) {
            int p = (tY * 6 + nf) * WW + tX * 16 + m;
            out[imgOut + (long)oc * HW + p] = acc[nf][reg] + bv;
        }
    }
}

// ---------------------------------------------------------------------------
extern "C" void kernel_launch(void* const* d_in, const int* in_sizes, int n_in,
                              void* d_out, int out_size, void* d_ws, size_t ws_size,
                              hipStream_t stream)
{
    const float* input  = (const float*)d_in[0];
    const float* fuse_w = (const float*)d_in[1];
    const float* fuse_b = (const float*)d_in[2];
    const float* om_w   = (const float*)d_in[3];
    const float* om_b   = (const float*)d_in[4];
    const float* dcn_w  = (const float*)d_in[5];
    const float* dcn_b  = (const float*)d_in[6];
    const float* conv_w = (const float*)d_in[7];
    const float* conv_b = (const float*)d_in[8];
    const float* cat_w  = (const float*)d_in[9];
    const float* cat_b  = (const float*)d_in[10];
    float* out = (float*)d_out;

    char* w = (char*)d_ws;
    size_t off = 0;
    auto alloc = [&](size_t bytes) { void* p = w + off; off += (bytes + 255) & ~(size_t)255; return p; };

    unsigned short* xbf    = (unsigned short*)alloc(10L * HW * 64 * 2);
    unsigned short* hbuf   = (unsigned short*)alloc(4L * HW * 128 * 2);
    unsigned short* comb   = (unsigned short*)alloc(4L * HW * 64 * 2);
    float*          omb    = (float*)alloc(4L * 216 * HW * 4);
    unsigned short* fusedb = (unsigned short*)alloc(4L * HW * 256 * 2);
    float*          cbufs  = (float*)alloc(4L * HW * 64 * 4);
    unsigned short* hseqb  = (unsigned short*)alloc(10L * HW * 128 * 2);
    unsigned short* Wf = (unsigned short*)alloc(9L * 64 * 2 * 128 * 2);
    unsigned short* Wo = (unsigned short*)alloc(9L * 256 * 2 * 64 * 2);
    unsigned short* Wc = (unsigned short*)alloc(9L * 256 * 2 * 128 * 2);
    unsigned short* Wk = (unsigned short*)alloc(9L * 64 * 2 * 128 * 2);
    unsigned short* W1 = (unsigned short*)alloc(128L * 2 * 576 * 2);

    dim3 blk(256);
    wexp3_kernel<<<dim3(288), blk, 0, stream>>>(fuse_w, Wf, 64, 64, 128);
    wexp3_kernel<<<dim3(576), blk, 0, stream>>>(om_w, Wo, 216, 256, 64);
    wexp3_kernel<<<dim3(1152), blk, 0, stream>>>(conv_w, Wc, 256, 256, 128);
    wexp3_kernel<<<dim3(288), blk, 0, stream>>>(cat_w, Wk, 64, 64, 128);
    wexp1_kernel<<<dim3(288), blk, 0, stream>>>(dcn_w, W1);
    xprep_kernel<<<dim3(23040), blk, 0, stream>>>(input, xbf);

    hipMemsetAsync(hbuf, 0, 4L * HW * 128 * 2, stream);
    hipMemsetAsync(cbufs, 0, 4L * HW * 64 * 4, stream);

    for (int s = 0; s < TT; ++s) {
        int t0 = s, t1 = TT - 1 - s;
        fuse_conv<<<dim3(96, 1, 4), blk, 0, stream>>>(
            xbf, hbuf, Wf, fuse_b, comb, t0, t1);
        om_conv<<<dim3(96, 1, 4), dim3(1024), 0, stream>>>(
            comb, Wo, om_b, omb);
        conv1x1_fused<<<dim3(1152), dim3(256), 0, stream>>>(
            hbuf, omb, W1, dcn_b, fusedb);
        big_conv_gates<<<dim3(96, 1, 2), dim3(1024), 0, stream>>>(
            fusedb, Wc, conv_b, cbufs, hbuf, hseqb, t0, t1);
    }
    cat_conv<<<dim3(96, 1, 10), blk, 0, stream>>>(hseqb, Wk, cat_b, out);
}

// Round 18
// 1233.657 us; speedup vs baseline: 1.0581x; 1.0581x over previous
//
#include <hip/hip_runtime.h>
#include <math.h>

#define HH 96
#define WW 96
#define HW 9216
#define TT 5

typedef __attribute__((ext_vector_type(8))) short bf16x8;
typedef __attribute__((ext_vector_type(4))) float f32x4;

__device__ __forceinline__ float sigf(float x) { return 1.0f / (1.0f + expf(-x)); }
__device__ __forceinline__ unsigned short bhi(float x) {
    return (unsigned short)(__float_as_uint(x) >> 16);
}
__device__ __forceinline__ unsigned short blo(float x) {
    float h = __uint_as_float(__float_as_uint(x) & 0xffff0000u);
    return (unsigned short)(__float_as_uint(x - h) >> 16);
}
__device__ __forceinline__ float b2f(unsigned short u) {
    return __uint_as_float(((unsigned)u) << 16);
}

// ---------------------------------------------------------------------------
// Weight expansion: src [OC][IC][9] fp32 -> dst [9][OCP][2][IC] bf16 hi/lo.
// ---------------------------------------------------------------------------
__global__ __launch_bounds__(256) void wexp3_kernel(
    const float* __restrict__ w, unsigned short* __restrict__ dst,
    int OC, int OCP, int IC)
{
    long i = (long)blockIdx.x * 256 + threadIdx.x;
    int ic = (int)(i % IC);
    long r = i / IC;
    int oc = (int)(r % OCP);
    int tap = (int)(r / OCP);
    float v = (oc < OC) ? w[((long)oc * IC + ic) * 9 + tap] : 0.f;
    long base = (((long)tap * OCP + oc) * 2) * IC + ic;
    dst[base] = bhi(v);
    dst[base + IC] = blo(v);
}

// dcn_w [128][576] (576 = c*9+k) -> [128][2][576] with K re-ordered k-major:
// dst K-slot (k*64 + c) = src (c*9 + k).
__global__ __launch_bounds__(256) void wexp1_kernel(
    const float* __restrict__ w, unsigned short* __restrict__ dst)
{
    int i = blockIdx.x * 256 + threadIdx.x;   // over 128*576 dst slots
    int slot = i % 576;                        // k*64 + c
    int oc = i / 576;
    int k = slot >> 6, c = slot & 63;
    float v = w[(long)oc * 576 + c * 9 + k];
    dst[((long)oc * 2) * 576 + slot] = bhi(v);
    dst[((long)oc * 2 + 1) * 576 + slot] = blo(v);
}

// input [b][t][64][HW] fp32 -> xbf [(t*2+b)][p][64] bf16
__global__ __launch_bounds__(256) void xprep_kernel(
    const float* __restrict__ input, unsigned short* __restrict__ xbf)
{
    long i = (long)blockIdx.x * 256 + threadIdx.x;
    int p = (int)(i % HW);
    long r = i / HW;
    int c = (int)(r % 64);
    long bt = r / 64;
    int b = (int)(bt / TT), t = (int)(bt % TT);
    float v = input[i];
    xbf[(((long)(t * 2 + b) * HW) + p) * 64 + c] = bhi(v);
}

// ===========================================================================
// R18: R17's tile halving REVERTED (occupancy rose 27->32 but dur worsened:
// conv1x1 is gather-TRANSACTION-bound, not latency-bound). Back to 64px/
// 512thr; new lever = WAVE LANE REMAP: g0 = tid&7, cellb = tid>>3, so a
// wave = 8 pixels x 8 groups. The 8 lanes sharing a pixel consume its
// whole 256B record (4 lines, fully used) vs 64 px x 1 half-used line:
// corner-gather line-touches per wave halve (64 -> 32). Lane assignment
// only; LDS content after barrier identical -> bitwise-identical output.
// big/om/fuse/cat at R16 measured-best configs.
// ===========================================================================

// ---------------------------------------------------------------------------
// Fuse conv: x (single, ic 0..63) + h (hl, ic 64..127) -> comb bf16 NHWC.
// 6x16 tile, 4 waves, wave owns one oc-16 block. acc[6]=24 VGPR, rolling-B.
// ---------------------------------------------------------------------------
__global__ __launch_bounds__(256) void fuse_conv(
    const unsigned short* __restrict__ xbf,
    const unsigned short* __restrict__ hbuf,
    const unsigned short* __restrict__ Wf,   // [9][64][2][128]
    const float* __restrict__ bias,
    unsigned short* __restrict__ comb,
    int t0, int t1)
{
    __shared__ unsigned short sX[144 * 200];
    const int tid = threadIdx.x;
    const int wave = tid >> 6, lane = tid & 63;
    const int m = lane & 15, quad = lane >> 4;
    const int tY = blockIdx.x / 6, tX = blockIdx.x % 6;   // tY 0..15
    const int z = blockIdx.z;
    const int imgX = ((z < 2) ? t0 : t1) * 2 + (z & 1);

    const unsigned short* xb = xbf + (long)imgX * HW * 64;
    const unsigned short* hb = hbuf + (long)z * HW * 128;

    for (int i = tid; i < 144 * 24; i += 256) {
        int cell = i / 24, v = i - cell * 24;
        int row = cell / 18, col = cell - row * 18;
        int gy = tY * 6 + row - 1, gx = tX * 16 + col - 1;
        bool ok = (gy >= 0 && gy < HH && gx >= 0 && gx < WW);
        int p = gy * WW + gx;
        bf16x8 val = (bf16x8){0,0,0,0,0,0,0,0};
        int dst;
        if (v < 8) {
            if (ok) val = *(const bf16x8*)(xb + (long)p * 64 + v * 8);
            dst = cell * 200 + v * 8;
        } else {
            int v2 = v - 8;
            int pl = v2 >> 3, c = (v2 & 7) >> 2, g = v2 & 3;
            // hbuf record: [16 groups][hi8|lo8]; channels c*32+g*8 = group c*4+g
            if (ok) val = *(const bf16x8*)(hb + (long)p * 128 + (c * 4 + g) * 16 + pl * 8);
            dst = cell * 200 + 64 + (c * 2 + pl) * 32 + g * 8;
        }
        *(bf16x8*)&sX[dst] = val;
    }
    __syncthreads();

    f32x4 acc[6];
#pragma unroll
    for (int nf = 0; nf < 6; ++nf) acc[nf] = (f32x4){0.f, 0.f, 0.f, 0.f};

    // part 1: x channels (single precision), c = 0,1
#pragma unroll
    for (int c = 0; c < 2; ++c) {
#pragma unroll
        for (int kx = 0; kx < 3; ++kx) {
            bf16x8 Ah[3], Al[3];
#pragma unroll
            for (int ky = 0; ky < 3; ++ky) {
                const unsigned short* wp = Wf + (((long)(ky * 3 + kx) * 64 + wave * 16 + m) * 2) * 128 + c * 32 + quad * 8;
                Ah[ky] = *(const bf16x8*)wp;
                Al[ky] = *(const bf16x8*)(wp + 128);
            }
            bf16x8 B[8];
#pragma unroll
            for (int r = 0; r < 3; ++r)
                B[r] = *(const bf16x8*)&sX[(r * 18 + kx + m) * 200 + c * 32 + quad * 8];
#pragma unroll
            for (int nf = 0; nf < 6; ++nf) {
                if (nf) {
                    int r = nf + 2;
                    B[r] = *(const bf16x8*)&sX[(r * 18 + kx + m) * 200 + c * 32 + quad * 8];
                }
#pragma unroll
                for (int ky = 0; ky < 3; ++ky) {
                    acc[nf] = __builtin_amdgcn_mfma_f32_16x16x32_bf16(Ah[ky], B[nf + ky], acc[nf], 0, 0, 0);
                    acc[nf] = __builtin_amdgcn_mfma_f32_16x16x32_bf16(Al[ky], B[nf + ky], acc[nf], 0, 0, 0);
                }
            }
        }
    }
    // part 2: h channels (hl), c = 0,1
#pragma unroll
    for (int c = 0; c < 2; ++c) {
#pragma unroll
        for (int kx = 0; kx < 3; ++kx) {
            bf16x8 Ah[3], Al[3];
#pragma unroll
            for (int ky = 0; ky < 3; ++ky) {
                const unsigned short* wp = Wf + (((long)(ky * 3 + kx) * 64 + wave * 16 + m) * 2) * 128 + (2 + c) * 32 + quad * 8;
                Ah[ky] = *(const bf16x8*)wp;
                Al[ky] = *(const bf16x8*)(wp + 128);
            }
            bf16x8 Bh[8], Bl[8];
#pragma unroll
            for (int r = 0; r < 3; ++r) {
                int base = (r * 18 + kx + m) * 200 + 64 + (c * 2) * 32 + quad * 8;
                Bh[r] = *(const bf16x8*)&sX[base];
                Bl[r] = *(const bf16x8*)&sX[base + 32];
            }
#pragma unroll
            for (int nf = 0; nf < 6; ++nf) {
                if (nf) {
                    int r = nf + 2;
                    int base = (r * 18 + kx + m) * 200 + 64 + (c * 2) * 32 + quad * 8;
                    Bh[r] = *(const bf16x8*)&sX[base];
                    Bl[r] = *(const bf16x8*)&sX[base + 32];
                }
#pragma unroll
                for (int ky = 0; ky < 3; ++ky) {
                    acc[nf] = __builtin_amdgcn_mfma_f32_16x16x32_bf16(Ah[ky], Bh[nf + ky], acc[nf], 0, 0, 0);
                    acc[nf] = __builtin_amdgcn_mfma_f32_16x16x32_bf16(Al[ky], Bh[nf + ky], acc[nf], 0, 0, 0);
                    acc[nf] = __builtin_amdgcn_mfma_f32_16x16x32_bf16(Ah[ky], Bl[nf + ky], acc[nf], 0, 0, 0);
                }
            }
        }
    }

    int ocl = wave * 16 + quad * 4;
    float b0 = bias[ocl], b1 = bias[ocl + 1], b2 = bias[ocl + 2], b3 = bias[ocl + 3];
#pragma unroll
    for (int nf = 0; nf < 6; ++nf) {
        int p = (tY * 6 + nf) * WW + tX * 16 + m;
        ushort4 hv;
        hv.x = bhi(acc[nf].x + b0); hv.y = bhi(acc[nf].y + b1);
        hv.z = bhi(acc[nf].z + b2); hv.w = bhi(acc[nf].w + b3);
        *(ushort4*)&comb[((long)z * HW + p) * 64 + ocl] = hv;
    }
}

// ---------------------------------------------------------------------------
// om conv: comb (single, IC=64) -> om fp32 NCHW (216 of 256 oc).
// R8-recipe clone (R12-measured win): 6x16 tile, 16-wave block, wave owns
// one oc-16 block, acc[6], rolling-3 B window, 8:1 MFMA:load.
// ---------------------------------------------------------------------------
__global__ __launch_bounds__(1024) void om_conv(
    const unsigned short* __restrict__ comb,
    const unsigned short* __restrict__ Wo,   // [9][256][2][64]
    const float* __restrict__ bias,
    float* __restrict__ om)                  // [z][216][HW]
{
    __shared__ unsigned short sX[144 * 72];
    const int tid = threadIdx.x;
    const int wave = tid >> 6, lane = tid & 63;
    const int m = lane & 15, quad = lane >> 4;
    const int tY = blockIdx.x / 6, tX = blockIdx.x % 6;   // tY 0..15
    const int z = blockIdx.z;
    const unsigned short* cbp = comb + (long)z * HW * 64;

    for (int i = tid; i < 144 * 8; i += 1024) {
        int cell = i >> 3, v = i & 7;
        int row = cell / 18, col = cell - row * 18;
        int gy = tY * 6 + row - 1, gx = tX * 16 + col - 1;
        bf16x8 val = (bf16x8){0,0,0,0,0,0,0,0};
        if (gy >= 0 && gy < HH && gx >= 0 && gx < WW)
            val = *(const bf16x8*)(cbp + (long)(gy * WW + gx) * 64 + v * 8);
        *(bf16x8*)&sX[cell * 72 + v * 8] = val;
    }
    __syncthreads();

    if (wave * 16 >= 216) return;   // oc blocks 14,15 are pure padding

    f32x4 acc[6];
#pragma unroll
    for (int nf = 0; nf < 6; ++nf) acc[nf] = (f32x4){0.f, 0.f, 0.f, 0.f};

#pragma unroll
    for (int c = 0; c < 2; ++c) {
#pragma unroll
        for (int kx = 0; kx < 3; ++kx) {
            bf16x8 Ah[3], Al[3];
#pragma unroll
            for (int ky = 0; ky < 3; ++ky) {
                const unsigned short* wp = Wo + (((long)(ky * 3 + kx) * 256 + wave * 16 + m) * 2) * 64 + c * 32 + quad * 8;
                Ah[ky] = *(const bf16x8*)wp;
                Al[ky] = *(const bf16x8*)(wp + 64);
            }
            bf16x8 B[8];
#pragma unroll
            for (int r = 0; r < 3; ++r)
                B[r] = *(const bf16x8*)&sX[(r * 18 + kx + m) * 72 + c * 32 + quad * 8];
#pragma unroll
            for (int nf = 0; nf < 6; ++nf) {
                if (nf) {
                    int r = nf + 2;
                    B[r] = *(const bf16x8*)&sX[(r * 18 + kx + m) * 72 + c * 32 + quad * 8];
                }
#pragma unroll
                for (int ky = 0; ky < 3; ++ky) {
                    acc[nf] = __builtin_amdgcn_mfma_f32_16x16x32_bf16(Ah[ky], B[nf + ky], acc[nf], 0, 0, 0);
                    acc[nf] = __builtin_amdgcn_mfma_f32_16x16x32_bf16(Al[ky], B[nf + ky], acc[nf], 0, 0, 0);
                }
            }
        }
    }

#pragma unroll
    for (int reg = 0; reg < 4; ++reg) {
        int oc = wave * 16 + quad * 4 + reg;
        if (oc < 216) {
            float bv = bias[oc];
#pragma unroll
            for (int nf = 0; nf < 6; ++nf) {
                int p = (tY * 6 + nf) * WW + tX * 16 + m;
                om[((long)z * 216 + oc) * HW + p] = acc[nf][reg] + bv;
            }
        }
    }
}

// ---------------------------------------------------------------------------
// FUSED deformable-sampling + 1x1 DCN einsum (512 threads, XCD-swizzled).
// WAVE REMAP: g0 = tid&7, cellb = tid>>3 -> wave = 8 pixels x 8 groups; the
// 8 lanes sharing a pixel consume its full 256B record (4 fully-used lines)
// vs 64 half-used lines: corner-gather transactions halve. Sampling
// expressions and LDS contents unchanged -> bitwise-identical output.
// hbuf record [16 groups][hi8|lo8] (R15 win).
// ---------------------------------------------------------------------------
__global__ __launch_bounds__(512) void conv1x1_fused(
    const unsigned short* __restrict__ hbuf,  // [4][p][16][2][8] group-interleaved
    const float* __restrict__ om,             // [4][216][HW]
    const unsigned short* __restrict__ w1,    // [128][2][576] k-major
    const float* __restrict__ bias,
    unsigned short* __restrict__ fused)       // [z][p][256] hl
{
    __shared__ unsigned short sX[64 * 76];
    const int tid  = threadIdx.x;
    const int wave = tid >> 6, lane = tid & 63;
    const int m = lane & 15, quad = lane >> 4;

    // bijective XCD swizzle over 576 = 8 XCDs x 72 chunks
    const int bid = blockIdx.x;
    const int work = (bid & 7) * 72 + (bid >> 3);
    const int zz = work / 144;
    const int pt = work - zz * 144;

    const float* omb = om + (long)zz * 216 * HW;
    const unsigned short* hz = hbuf + (long)zz * HW * 128;

    const int g0 = tid & 7;         // channel group (varies fastest in a wave)
    const int cellb = tid >> 3;     // 0..63 pixel within tile

    // Bilinear-sample 8 channels (group g0) at pixel p=pt*64+cell, tap cb.
    // Expression-identical to the original sampler -> bitwise-same bf16.
    auto sample = [&](int cell, int cb) -> bf16x8 {
        int p = pt * 64 + cell;
        int y = p / WW, x = p - y * WW;
        int ky = cb / 3, kx = cb - ky * 3;
        float offy = omb[(g0 * 18 + cb * 2) * HW + p];
        float offx = omb[(g0 * 18 + cb * 2 + 1) * HW + p];
        float mm = sigf(omb[(144 + g0 * 9 + cb) * HW + p]);
        float py = (float)(y + ky - 1) + offy;
        float px = (float)(x + kx - 1) + offx;
        float y0f = floorf(py), x0f = floorf(px);
        float wy = py - y0f, wx = px - x0f;
        int y0 = (int)y0f, x0 = (int)x0f;
        int y1 = y0 + 1, x1 = x0 + 1;
        bool vy0 = (y0 >= 0) && (y0 < HH), vy1 = (y1 >= 0) && (y1 < HH);
        bool vx0 = (x0 >= 0) && (x0 < WW), vx1 = (x1 >= 0) && (x1 < WW);
        int cy0 = min(max(y0, 0), HH - 1), cy1 = min(max(y1, 0), HH - 1);
        int cx0 = min(max(x0, 0), WW - 1), cx1 = min(max(x1, 0), WW - 1);
        long i00 = cy0 * WW + cx0, i01 = cy0 * WW + cx1;
        long i10 = cy1 * WW + cx0, i11 = cy1 * WW + cx1;
        float w00 = (1.f - wy) * (1.f - wx) * ((vy0 && vx0) ? mm : 0.f);
        float w01 = (1.f - wy) * wx         * ((vy0 && vx1) ? mm : 0.f);
        float w10 = wy * (1.f - wx)         * ((vy1 && vx0) ? mm : 0.f);
        float w11 = wy * wx                 * ((vy1 && vx1) ? mm : 0.f);
        // group-interleaved record: hi at p*128 + g0*16, lo at +8 (same 64B line)
        const unsigned short* hzb = hz + g0 * 16;
        bf16x8 h00 = *(const bf16x8*)(hzb + i00 * 128);
        bf16x8 l00 = *(const bf16x8*)(hzb + i00 * 128 + 8);
        bf16x8 h01 = *(const bf16x8*)(hzb + i01 * 128);
        bf16x8 l01 = *(const bf16x8*)(hzb + i01 * 128 + 8);
        bf16x8 h10 = *(const bf16x8*)(hzb + i10 * 128);
        bf16x8 l10 = *(const bf16x8*)(hzb + i10 * 128 + 8);
        bf16x8 h11 = *(const bf16x8*)(hzb + i11 * 128);
        bf16x8 l11 = *(const bf16x8*)(hzb + i11 * 128 + 8);
        bf16x8 outv;
#pragma unroll
        for (int cg = 0; cg < 8; ++cg) {
            float v00 = b2f((unsigned short)h00[cg]) + b2f((unsigned short)l00[cg]);
            float v01 = b2f((unsigned short)h01[cg]) + b2f((unsigned short)l01[cg]);
            float v10 = b2f((unsigned short)h10[cg]) + b2f((unsigned short)l10[cg]);
            float v11 = b2f((unsigned short)h11[cg]) + b2f((unsigned short)l11[cg]);
            float v = w00 * v00 + w01 * v01 + w10 * v10 + w11 * v11;
            outv[cg] = (short)bhi(v);
        }
        return outv;
    };

    f32x4 acc[4];
#pragma unroll
    for (int nf = 0; nf < 4; ++nf) acc[nf] = (f32x4){0.f, 0.f, 0.f, 0.f};

    for (int cb = 0; cb < 9; ++cb) {
        if (cb) __syncthreads();
        bf16x8 R0 = sample(cellb, cb);
        *(bf16x8*)&sX[cellb * 76 + g0 * 8] = R0;
        __syncthreads();

        bf16x8 Bv[2][4];
#pragma unroll
        for (int sub = 0; sub < 2; ++sub)
#pragma unroll
            for (int nf = 0; nf < 4; ++nf)
                Bv[sub][nf] = *(const bf16x8*)&sX[(nf * 16 + m) * 76 + sub * 32 + quad * 8];
        bf16x8 Ah[2], Al[2];
#pragma unroll
        for (int sub = 0; sub < 2; ++sub) {
            const unsigned short* wp = w1 + ((long)(wave * 16 + m) * 2) * 576
                                       + cb * 64 + sub * 32 + quad * 8;
            Ah[sub] = *(const bf16x8*)wp;
            Al[sub] = *(const bf16x8*)(wp + 576);
        }
#pragma unroll
        for (int sub = 0; sub < 2; ++sub)
#pragma unroll
            for (int nf = 0; nf < 4; ++nf) {
                acc[nf] = __builtin_amdgcn_mfma_f32_16x16x32_bf16(
                    Ah[sub], Bv[sub][nf], acc[nf], 0, 0, 0);
                acc[nf] = __builtin_amdgcn_mfma_f32_16x16x32_bf16(
                    Al[sub], Bv[sub][nf], acc[nf], 0, 0, 0);
            }
    }

    {
        int ocl = wave * 16 + quad * 4;
        float b0 = bias[ocl], b1 = bias[ocl + 1], b2 = bias[ocl + 2], b3 = bias[ocl + 3];
#pragma unroll
        for (int nf = 0; nf < 4; ++nf) {
            int p = pt * 64 + nf * 16 + m;
            float v0 = fmaxf(acc[nf].x + b0, 0.f);
            float v1 = fmaxf(acc[nf].y + b1, 0.f);
            float v2 = fmaxf(acc[nf].z + b2, 0.f);
            float v3 = fmaxf(acc[nf].w + b3, 0.f);
            unsigned short* op = fused + ((long)zz * HW + p) * 256 + ocl;
            ushort4 hv, lv;
            hv.x = bhi(v0); hv.y = bhi(v1); hv.z = bhi(v2); hv.w = bhi(v3);
            lv.x = blo(v0); lv.y = blo(v1); lv.z = blo(v2); lv.w = blo(v3);
            *(ushort4*)op = hv;
            *(ushort4*)(op + 128) = lv;
        }
    }
}

// ---------------------------------------------------------------------------
// Big conv (IC=128 hl, OC=256) FUSED with LSTM gates. Z-PAIRED:
// block = one 6x16 tile x two z-planes (zp, zp+2), both staged in LDS
// (2 x 38016 ush = 152064 B, 1 block/CU). Per (c,kx): 6 weight loads feed
// 2x54 = 108 MFMAs. Grid 96x2 = 192 blocks. R16-measured win; unchanged.
// ---------------------------------------------------------------------------
__global__ __launch_bounds__(1024) void big_conv_gates(
    const unsigned short* __restrict__ fusedb,  // [z][p][256] hl
    const unsigned short* __restrict__ Wc,      // [9][256][2][128]
    const float* __restrict__ bias,
    float* __restrict__ cst,                    // [z][p][64] fp32
    unsigned short* __restrict__ hbuf,          // [z][p][16][2][8] group-interleaved
    unsigned short* __restrict__ hseq,          // [(t*2+b)][p][128]
    int t0, int t1)
{
    // 2 planes x 144 cells x 264 ush = 152064 B. Gates region (after both
    // K-loops) reuses the front: 3 x 96 x 68 floats = 78336 B <= 152064.
    __shared__ unsigned short sX[2][144 * 264];
    const int tid = threadIdx.x;
    const int wave = tid >> 6, lane = tid & 63;
    const int m = lane & 15, quad = lane >> 4;
    const int tY = blockIdx.x / 6, tX = blockIdx.x % 6;   // tY 0..15
    const int zp = blockIdx.z;                             // 0,1: z = zp + zi*2

#pragma unroll
    for (int zi = 0; zi < 2; ++zi) {
        const unsigned short* fb = fusedb + (long)(zp + zi * 2) * HW * 256;
        for (int i = tid; i < 144 * 32; i += 1024) {
            int cell = i >> 5, v = i & 31;
            int row = cell / 18, col = cell - row * 18;
            int gy = tY * 6 + row - 1, gx = tX * 16 + col - 1;
            int pl = v >> 4, c = (v & 15) >> 2, g = v & 3;
            bf16x8 val = (bf16x8){0,0,0,0,0,0,0,0};
            if (gy >= 0 && gy < HH && gx >= 0 && gx < WW)
                val = *(const bf16x8*)(fb + (long)(gy * WW + gx) * 256 + pl * 128 + c * 32 + g * 8);
            *(bf16x8*)&sX[zi][cell * 264 + (c * 2 + pl) * 32 + g * 8] = val;
        }
    }
    __syncthreads();

    f32x4 acc[2][6];
#pragma unroll
    for (int zi = 0; zi < 2; ++zi)
#pragma unroll
        for (int nf = 0; nf < 6; ++nf) acc[zi][nf] = (f32x4){0.f, 0.f, 0.f, 0.f};

#pragma unroll
    for (int c = 0; c < 4; ++c) {
#pragma unroll
        for (int kx = 0; kx < 3; ++kx) {
            bf16x8 Ah[3], Al[3];
#pragma unroll
            for (int ky = 0; ky < 3; ++ky) {
                const unsigned short* wp = Wc + (((long)(ky * 3 + kx) * 256 + wave * 16 + m) * 2) * 128 + c * 32 + quad * 8;
                Ah[ky] = *(const bf16x8*)wp;
                Al[ky] = *(const bf16x8*)(wp + 128);
            }
#pragma unroll
            for (int zi = 0; zi < 2; ++zi) {
                bf16x8 Bh[8], Bl[8];
#pragma unroll
                for (int r = 0; r < 3; ++r) {
                    int base = (r * 18 + kx + m) * 264 + (c * 2) * 32 + quad * 8;
                    Bh[r] = *(const bf16x8*)&sX[zi][base];
                    Bl[r] = *(const bf16x8*)&sX[zi][base + 32];
                }
#pragma unroll
                for (int nf = 0; nf < 6; ++nf) {
                    if (nf) {
                        int r = nf + 2;
                        int base = (r * 18 + kx + m) * 264 + (c * 2) * 32 + quad * 8;
                        Bh[r] = *(const bf16x8*)&sX[zi][base];
                        Bl[r] = *(const bf16x8*)&sX[zi][base + 32];
                    }
#pragma unroll
                    for (int ky = 0; ky < 3; ++ky) {
                        acc[zi][nf] = __builtin_amdgcn_mfma_f32_16x16x32_bf16(Ah[ky], Bh[nf + ky], acc[zi][nf], 0, 0, 0);
                        acc[zi][nf] = __builtin_amdgcn_mfma_f32_16x16x32_bf16(Al[ky], Bh[nf + ky], acc[zi][nf], 0, 0, 0);
                        acc[zi][nf] = __builtin_amdgcn_mfma_f32_16x16x32_bf16(Ah[ky], Bl[nf + ky], acc[zi][nf], 0, 0, 0);
                    }
                }
            }
        }
    }

    // ---- gates epilogue (per z-plane; gates region reuses staging LDS) ----
    // wave w owns oc block w: ci = w0-3, cf = w4-7, co = w8-11, cg = w12-15.
    float* sG = (float*)&sX[0][0];
    float ba[4];
    {
        int oc0 = wave * 16 + quad * 4;
#pragma unroll
        for (int r = 0; r < 4; ++r) ba[r] = bias[oc0 + r];
    }
#pragma unroll
    for (int zi = 0; zi < 2; ++zi) {
        const int z = zp + zi * 2;
        __syncthreads();   // staging reads (zi=0) / prior gate reads (zi=1) done
        if (wave >= 4) {
            int reg = (wave >> 2) - 1;            // 0=cf, 1=co, 2=cg
            int chb = (wave & 3) * 16 + quad * 4;
#pragma unroll
            for (int nf = 0; nf < 6; ++nf) {
                int px = nf * 16 + m;
                float* f = &sG[reg * 96 * 68 + (long)px * 68 + chb];
#pragma unroll
                for (int r = 0; r < 4; ++r) f[r] = acc[zi][nf][r] + ba[r];
            }
        }
        __syncthreads();
        if (wave < 4) {
            int t = (zi == 0) ? t0 : t1;
            int b = zp & 1, dir = zi;
            int chb = wave * 16 + quad * 4;
            unsigned short* hsq = hseq + ((long)(t * 2 + b) * HW) * 128 + dir * 64;
#pragma unroll
            for (int nf = 0; nf < 6; ++nf) {
                int px = nf * 16 + m;
                int p = (tY * 6 + nf) * WW + tX * 16 + m;
                float4 cf4 = *(float4*)&sG[0 * 96 * 68 + (long)px * 68 + chb];
                float4 co4 = *(float4*)&sG[1 * 96 * 68 + (long)px * 68 + chb];
                float4 cg4 = *(float4*)&sG[2 * 96 * 68 + (long)px * 68 + chb];
                float* cp = &cst[((long)z * HW + p) * 64 + chb];
                float4 cold = *(float4*)cp;
                float cfv[4] = {cf4.x, cf4.y, cf4.z, cf4.w};
                float cov[4] = {co4.x, co4.y, co4.z, co4.w};
                float cgv[4] = {cg4.x, cg4.y, cg4.z, cg4.w};
                float coldv[4] = {cold.x, cold.y, cold.z, cold.w};
                float c2v[4], h2v[4];
#pragma unroll
                for (int r = 0; r < 4; ++r) {
                    float civ = acc[zi][nf][r] + ba[r];
                    float c2 = sigf(cfv[r]) * coldv[r] + sigf(civ) * tanhf(cgv[r]);
                    float h2 = sigf(cov[r]) * tanhf(c2);
                    c2v[r] = c2; h2v[r] = h2;
                }
                *(float4*)cp = (float4){c2v[0], c2v[1], c2v[2], c2v[3]};
                // group-interleaved hbuf record: hi at group*16 + (chb&7), lo at +8
                unsigned short* hp = hbuf + ((long)z * HW + p) * 128 + (chb >> 3) * 16 + (chb & 7);
                ushort4 hv = {bhi(h2v[0]), bhi(h2v[1]), bhi(h2v[2]), bhi(h2v[3])};
                ushort4 lv = {blo(h2v[0]), blo(h2v[1]), blo(h2v[2]), blo(h2v[3])};
                *(ushort4*)hp = hv;
                *(ushort4*)(hp + 8) = lv;
                *(ushort4*)&hsq[(long)p * 128 + chb] = hv;
            }
        }
    }
}

// ---------------------------------------------------------------------------
// cat conv: hseq (single-plane, IC=128) -> out fp32 NCHW with (t,b) permute.
// 6x16 tile: grid 96x10 = 960 blocks, acc[6], rolling-B.
// ---------------------------------------------------------------------------
__global__ __launch_bounds__(256) void cat_conv(
    const unsigned short* __restrict__ hseq,
    const unsigned short* __restrict__ Wk,     // [9][64][2][128]
    const float* __restrict__ bias,
    float* __restrict__ out)
{
    __shared__ unsigned short sX[144 * 136];
    const int tid = threadIdx.x;
    const int wave = tid >> 6, lane = tid & 63;
    const int m = lane & 15, quad = lane >> 4;
    const int tY = blockIdx.x / 6, tX = blockIdx.x % 6;   // tY 0..15
    const int img = blockIdx.z;
    const unsigned short* hp = hseq + (long)img * HW * 128;

    for (int i = tid; i < 144 * 16; i += 256) {
        int cell = i >> 4, v = i & 15;
        int row = cell / 18, col = cell - row * 18;
        int gy = tY * 6 + row - 1, gx = tX * 16 + col - 1;
        bf16x8 val = (bf16x8){0,0,0,0,0,0,0,0};
        if (gy >= 0 && gy < HH && gx >= 0 && gx < WW)
            val = *(const bf16x8*)(hp + (long)(gy * WW + gx) * 128 + v * 8);
        *(bf16x8*)&sX[cell * 136 + v * 8] = val;
    }
    __syncthreads();

    f32x4 acc[6];
#pragma unroll
    for (int nf = 0; nf < 6; ++nf) acc[nf] = (f32x4){0.f, 0.f, 0.f, 0.f};

#pragma unroll
    for (int c = 0; c < 4; ++c) {
#pragma unroll
        for (int kx = 0; kx < 3; ++kx) {
            bf16x8 Ah[3], Al[3];
#pragma unroll
            for (int ky = 0; ky < 3; ++ky) {
                const unsigned short* wp = Wk + (((long)(ky * 3 + kx) * 64 + wave * 16 + m) * 2) * 128 + c * 32 + quad * 8;
                Ah[ky] = *(const bf16x8*)wp;
                Al[ky] = *(const bf16x8*)(wp + 128);
            }
            bf16x8 B[8];
#pragma unroll
            for (int r = 0; r < 3; ++r)
                B[r] = *(const bf16x8*)&sX[(r * 18 + kx + m) * 136 + c * 32 + quad * 8];
#pragma unroll
            for (int nf = 0; nf < 6; ++nf) {
                if (nf) {
                    int r = nf + 2;
                    B[r] = *(const bf16x8*)&sX[(r * 18 + kx + m) * 136 + c * 32 + quad * 8];
                }
#pragma unroll
                for (int ky = 0; ky < 3; ++ky) {
                    acc[nf] = __builtin_amdgcn_mfma_f32_16x16x32_bf16(Ah[ky], B[nf + ky], acc[nf], 0, 0, 0);
                    acc[nf] = __builtin_amdgcn_mfma_f32_16x16x32_bf16(Al[ky], B[nf + ky], acc[nf], 0, 0, 0);
                }
            }
        }
    }

    int t = img >> 1, b = img & 1;
    long imgOut = (long)(b * TT + t) * 64 * HW;
#pragma unroll
    for (int reg = 0; reg < 4; ++reg) {
        int oc = wave * 16 + quad * 4 + reg;
        float bv = bias[oc];
#pragma unroll
        for (int nf = 0; nf < 6; ++nf) {
            int p = (tY * 6 + nf) * WW + tX * 16 + m;
            out[imgOut + (long)oc * HW + p] = acc[nf][reg] + bv;
        }
    }
}

// ---------------------------------------------------------------------------
extern "C" void kernel_launch(void* const* d_in, const int* in_sizes, int n_in,
                              void* d_out, int out_size, void* d_ws, size_t ws_size,
                              hipStream_t stream)
{
    const float* input  = (const float*)d_in[0];
    const float* fuse_w = (const float*)d_in[1];
    const float* fuse_b = (const float*)d_in[2];
    const float* om_w   = (const float*)d_in[3];
    const float* om_b   = (const float*)d_in[4];
    const float* dcn_w  = (const float*)d_in[5];
    const float* dcn_b  = (const float*)d_in[6];
    const float* conv_w = (const float*)d_in[7];
    const float* conv_b = (const float*)d_in[8];
    const float* cat_w  = (const float*)d_in[9];
    const float* cat_b  = (const float*)d_in[10];
    float* out = (float*)d_out;

    char* w = (char*)d_ws;
    size_t off = 0;
    auto alloc = [&](size_t bytes) { void* p = w + off; off += (bytes + 255) & ~(size_t)255; return p; };

    unsigned short* xbf    = (unsigned short*)alloc(10L * HW * 64 * 2);
    unsigned short* hbuf   = (unsigned short*)alloc(4L * HW * 128 * 2);
    unsigned short* comb   = (unsigned short*)alloc(4L * HW * 64 * 2);
    float*          omb    = (float*)alloc(4L * 216 * HW * 4);
    unsigned short* fusedb = (unsigned short*)alloc(4L * HW * 256 * 2);
    float*          cbufs  = (float*)alloc(4L * HW * 64 * 4);
    unsigned short* hseqb  = (unsigned short*)alloc(10L * HW * 128 * 2);
    unsigned short* Wf = (unsigned short*)alloc(9L * 64 * 2 * 128 * 2);
    unsigned short* Wo = (unsigned short*)alloc(9L * 256 * 2 * 64 * 2);
    unsigned short* Wc = (unsigned short*)alloc(9L * 256 * 2 * 128 * 2);
    unsigned short* Wk = (unsigned short*)alloc(9L * 64 * 2 * 128 * 2);
    unsigned short* W1 = (unsigned short*)alloc(128L * 2 * 576 * 2);

    dim3 blk(256);
    wexp3_kernel<<<dim3(288), blk, 0, stream>>>(fuse_w, Wf, 64, 64, 128);
    wexp3_kernel<<<dim3(576), blk, 0, stream>>>(om_w, Wo, 216, 256, 64);
    wexp3_kernel<<<dim3(1152), blk, 0, stream>>>(conv_w, Wc, 256, 256, 128);
    wexp3_kernel<<<dim3(288), blk, 0, stream>>>(cat_w, Wk, 64, 64, 128);
    wexp1_kernel<<<dim3(288), blk, 0, stream>>>(dcn_w, W1);
    xprep_kernel<<<dim3(23040), blk, 0, stream>>>(input, xbf);

    hipMemsetAsync(hbuf, 0, 4L * HW * 128 * 2, stream);
    hipMemsetAsync(cbufs, 0, 4L * HW * 64 * 4, stream);

    for (int s = 0; s < TT; ++s) {
        int t0 = s, t1 = TT - 1 - s;
        fuse_conv<<<dim3(96, 1, 4), blk, 0, stream>>>(
            xbf, hbuf, Wf, fuse_b, comb, t0, t1);
        om_conv<<<dim3(96, 1, 4), dim3(1024), 0, stream>>>(
            comb, Wo, om_b, omb);
        conv1x1_fused<<<dim3(576), dim3(512), 0, stream>>>(
            hbuf, omb, W1, dcn_b, fusedb);
        big_conv_gates<<<dim3(96, 1, 2), dim3(1024), 0, stream>>>(
            fusedb, Wc, conv_b, cbufs, hbuf, hseqb, t0, t1);
    }
    cat_conv<<<dim3(96, 1, 10), blk, 0, stream>>>(hseqb, Wk, cat_b, out);
}